// Round 2
// 954.883 us; speedup vs baseline: 1.0135x; 1.0135x over previous
//
#include <hip/hip_runtime.h>

// snntorch Synaptic scan, reset_mechanism='zero'.
// T=512, B=32, N=4096. x: (T,B,N) f32. out: [spk | syn | mem], each (T,B,N) f32.
// Per step: keep = (mem_prev <= thr); syn' = a*syn + x; mem' = b*mem + syn';
//           syn' *= keep; mem' *= keep; spk = (mem' > thr).
//
// R1 (resubmitted after GPU-acquisition timeout; no measurement happened):
// latency-hiding rewrite. R0 kernel was float4 lanes -> 512 waves total =
// 2 waves/CU with depth-1 prefetch: each iteration serially eats a ~900cy HBM
// load latency (~2KB in flight/CU => ~1.4 TB/s load ceiling).
//  - scalar element per lane: 131072 threads = 2048 waves = 8 waves/CU
//  - depth-4 x prefetch FIFO (named registers, compile-time indexed)
//  - nontemporal stores: outputs are streamed, never re-read
// Numerics: __fmul_rn/__fadd_rn forbid FMA contraction -> bit-match fp32 ref
// (spk is binary; a flipped borderline spike = absmax 1.0, so op order is kept
// exactly as the previously-passing kernel).

#define T_STEPS 512
#define BN      131072          // 32*4096 elements per timestep

__global__ __launch_bounds__(256) void snn_synaptic_kernel(
    const float* __restrict__ x, float* __restrict__ out) {
  const int i = blockIdx.x * 256 + threadIdx.x;   // 0 .. BN-1

  float* __restrict__ spk_o = out;
  float* __restrict__ syn_o = out + (long long)T_STEPS * BN;
  float* __restrict__ mem_o = out + 2LL * T_STEPS * BN;

  float syn = 0.f, mem = 0.f;

  // prefetch FIFO: x for steps t, t+1, t+2, t+3 (4 loads in flight per wave)
  float x0 = x[i];
  float x1 = x[1 * BN + i];
  float x2 = x[2 * BN + i];
  float x3 = x[3 * BN + i];

  for (int t = 0; t < T_STEPS; t += 4) {
    // prefetch t+4..t+7; final group clamps back to t..t+3 (harmless reload)
    const int pb = ((t + 4 < T_STEPS) ? (t + 4) : t) * BN + i;  // max 67.1M, fits int
    const float n0 = x[pb];
    const float n1 = x[pb + BN];
    const float n2 = x[pb + 2 * BN];
    const float n3 = x[pb + 3 * BN];

    #define STEP(tt, XV)                                           \
      {                                                            \
        const float keep = (mem > 2.0f) ? 0.0f : 1.0f;             \
        syn = __fadd_rn(__fmul_rn(0.1f, syn), XV);                 \
        mem = __fadd_rn(__fmul_rn(0.96f, mem), syn);               \
        syn *= keep;                                               \
        mem *= keep;                                               \
        const float spk = (mem > 2.0f) ? 1.0f : 0.0f;              \
        const int o = (tt) * BN + i;                               \
        __builtin_nontemporal_store(spk, spk_o + o);               \
        __builtin_nontemporal_store(syn, syn_o + o);               \
        __builtin_nontemporal_store(mem, mem_o + o);               \
      }
    STEP(t + 0, x0) STEP(t + 1, x1) STEP(t + 2, x2) STEP(t + 3, x3)
    #undef STEP

    x0 = n0; x1 = n1; x2 = n2; x3 = n3;
  }
}

extern "C" void kernel_launch(void* const* d_in, const int* in_sizes, int n_in,
                              void* d_out, int out_size, void* d_ws, size_t ws_size,
                              hipStream_t stream) {
  const float* x = (const float*)d_in[0];
  float* out = (float*)d_out;
  snn_synaptic_kernel<<<dim3(BN / 256), dim3(256), 0, stream>>>(x, out);
}